// Round 9
// baseline (172.830 us; speedup 1.0000x reference)
//
#include <hip/hip_runtime.h>

// Model_47510928228872: 2-layer bidirectional LSTM (H=3) + linear + sigmoid.
// B=8192, T=512, fp32.
//
// Round 9: phase restructure. True serial depth = 1024 steps:
//   KA: l0-fwd AND l0-bwd fused in ONE wave-stream (16 lanes/batch: octet0 =
//       fwd, octet1 = bwd; same instructions, per-lane data/addresses) ->
//       2048 waves = 2 waves/SIMD -> latency bubbles filled by the 2nd wave.
//   KB: l1-fwd (gate-split, 6-wide input from y0f,y0b) + 1-step l1-bwd +
//       linear head. 1024 waves.
// Gate-split cell (proven in K1): quad q0 owns packed (i,f) rows, q1 owns
// (g,o); rows prescaled by -log2e (sigma) / -2log2e (tanh); exchange via
// row_shl:4 / row_shr:4; both quads redundantly update c,h.
// y0f/y0b layout [B][64 blk][3 j][8 s], slot t = h(t) (UNSHIFTED).

#define B_ 8192
#define T_ 512
#define LOG2E 1.4426950408889634f

typedef float v2f __attribute__((ext_vector_type(2)));

__device__ __forceinline__ float rcp_(float x)  { return __builtin_amdgcn_rcpf(x); }
__device__ __forceinline__ float exp2_(float x) { return __builtin_amdgcn_exp2f(x); }
__device__ __forceinline__ float sigm_(float x) {
  return rcp_(1.0f + exp2_(-LOG2E * x));
}
__device__ __forceinline__ float tanh_(float x) {
  return 1.0f - 2.0f * rcp_(1.0f + exp2_(2.0f * LOG2E * x));
}
// activation on PRESCALED preact: rcp(1+exp2(p))
__device__ __forceinline__ float act_(float p) { return rcp_(1.f + exp2_(p)); }

__device__ __forceinline__ v2f sp(float s) { return (v2f){s, s}; }
__device__ __forceinline__ v2f pkfma(v2f a, float b, v2f c) {
  return __builtin_elementwise_fma(a, sp(b), c);
}

template <int CTRL>
__device__ __forceinline__ float dppf(float v) {
  int s = __float_as_int(v);
  return __int_as_float(__builtin_amdgcn_update_dpp(s, s, CTRL, 0xF, 0xF, false));
}
#define QP0 0x00   // quad_perm broadcast lane0 of quad
#define QP1 0x55
#define QP2 0xAA
#define SHL4 0x104 // row_shl:4 (lane i <- i+4)
#define SHR4 0x114 // row_shr:4 (lane i <- i-4)

// Shared gate-split step body (3 parallel MAC chains are built by caller into
// pv; here from pv -> c,h update + broadcast). avx/dvx: q0 (1,0), q1 (2,-1).
#define CELL_TAIL(HOUT)                                                   \
    float r0v = act_(pv.x);                                               \
    float ayv = act_(pv.y);            /* sigma(f) (q0) / sigma(o) (q1)*/ \
    float axv = __builtin_fmaf(avx, r0v, dvx); /* i (q0) / tanh g (q1) */ \
    float slx = dppf<SHL4>(axv), sly = dppf<SHL4>(ayv);                   \
    float srx = dppf<SHR4>(axv), sry = dppf<SHR4>(ayv);                   \
    float pig = axv * (qgo ? srx : slx);   /* i*g on both quads */        \
    float gf  = qgo ? sry : ayv;                                          \
    float gO  = qgo ? ayv : sly;                                          \
    c = __builtin_fmaf(gf, c, pig);                                       \
    float th = __builtin_fmaf(                                            \
        2.f, rcp_(1.f + exp2_(-2.f * LOG2E * c)), -1.f);                  \
    h = gO * th;                                                          \
    ha0 = dppf<QP0>(h); ha1 = dppf<QP1>(h); ha2 = dppf<QP2>(h);           \
    HOUT = h;

// =================== Kernel A: layer-0 fwd + bwd (16 lanes/batch) ===========
__global__ __launch_bounds__(256, 2) void lstm_l0_both(
    const float* __restrict__ x,       // [B][T][3]
    const float* __restrict__ Wf_ih, const float* __restrict__ Wf_hh,
    const float* __restrict__ bf_ih, const float* __restrict__ bf_hh,
    const float* __restrict__ Wr_ih, const float* __restrict__ Wr_hh,
    const float* __restrict__ br_ih, const float* __restrict__ br_hh,
    float* __restrict__ y0f,           // [B][64][3][8], slot t = h_fwd(t)
    float* __restrict__ y0b)           // [B][64][3][8], slot t = h_bwd(t)
{
  int tid  = blockIdx.x * 256 + threadIdx.x;
  int b    = tid >> 4;
  int lane = tid & 15;
  bool dirb = lane >= 8;              // octet 1 = backward direction
  bool qgo  = (lane & 4) != 0;        // quad role: (i,f) vs (g,o)
  int j = lane & 3; int jj = (j < 3) ? j : 0;
  const int ra = (qgo ? 6 : 0) + jj, rb = ra + 3;
  const float kx = qgo ? (-2.f * LOG2E) : (-LOG2E);
  const float ky = -LOG2E;
  const float avx = qgo ? 2.f : 1.f;
  const float dvx = qgo ? -1.f : 0.f;

  const float* Wi = dirb ? Wr_ih : Wf_ih;
  const float* Wh = dirb ? Wr_hh : Wf_hh;
  const float* bi = dirb ? br_ih : bf_ih;
  const float* bh = dirb ? br_hh : bf_hh;

  v2f w0 = {Wi[ra*3+0]*kx, Wi[rb*3+0]*ky},
      w1 = {Wi[ra*3+1]*kx, Wi[rb*3+1]*ky},
      w2 = {Wi[ra*3+2]*kx, Wi[rb*3+2]*ky};
  v2f u0 = {Wh[ra*3+0]*kx, Wh[rb*3+0]*ky},
      u1 = {Wh[ra*3+1]*kx, Wh[rb*3+1]*ky},
      u2 = {Wh[ra*3+2]*kx, Wh[rb*3+2]*ky};
  v2f b2 = {(bi[ra]+bh[ra])*kx, (bi[rb]+bh[rb])*ky};

  float h = 0.f, c = 0.f, ha0 = 0.f, ha1 = 0.f, ha2 = 0.f;

  const float4* xq = (const float4*)(x + (size_t)b * (T_ * 3));
  // per-lane walking offsets (float4 units): fwd ascends, bwd descends
  int offA  = dirb ? 63 * 6 : 0;
  int offB  = offA + (dirb ? -6 : 6);
  int dstep = dirb ? -12 : 12;
  // store pointer walks blocks in the same per-octet order
  float* ywp = (dirb ? y0b : y0f) + (size_t)b * (T_ * 3) + jj * 8
             + (dirb ? 63 * 24 : 0);
  int ystep = dirb ? -24 : 24;

  float hs0, hs1, hs2, hs3, hs4, hs5, hs6, hs7;
  float4 p0, p1, p2, p3, p4, p5, q0, q1, q2, q3, q4, q5;

#define LDA(off, r0_, r1_, r2_, r3_, r4_, r5_) do {                       \
    const float4* _p = xq + (off);                                        \
    r0_ = _p[0]; r1_ = _p[1]; r2_ = _p[2];                                \
    r3_ = _p[3]; r4_ = _p[4]; r5_ = _p[5];                                \
    __builtin_amdgcn_sched_barrier(0); } while (0)

  // One step; fwd inputs (xf*), bwd inputs (xb*) selected per-lane.
#define STEPA(xf0, xf1, xf2, xb0, xb1, xb2, HOUT) do {                    \
    float x0 = dirb ? (xb0) : (xf0);                                      \
    float x1 = dirb ? (xb1) : (xf1);                                      \
    float x2 = dirb ? (xb2) : (xf2);                                      \
    v2f pv = pkfma(w0, x0, b2); pv = pkfma(w1, x1, pv);                   \
    pv = pkfma(w2, x2, pv);                                               \
    v2f uv = u0 * sp(ha0); uv = pkfma(u1, ha1, uv);                       \
    uv = pkfma(u2, ha2, uv);                                              \
    pv = pv + uv;                                                         \
    CELL_TAIL(HOUT) } while (0)

  // fwd: slots 0..7 ascending; bwd: slots 7..0 (t descending) — same regs.
#define PROCA(r0_, r1_, r2_, r3_, r4_, r5_) do {                          \
    STEPA(r0_.x, r0_.y, r0_.z,  r5_.y, r5_.z, r5_.w, hs0);                \
    STEPA(r0_.w, r1_.x, r1_.y,  r4_.z, r4_.w, r5_.x, hs1);                \
    STEPA(r1_.z, r1_.w, r2_.x,  r3_.w, r4_.x, r4_.y, hs2);                \
    STEPA(r2_.y, r2_.z, r2_.w,  r3_.x, r3_.y, r3_.z, hs3);                \
    STEPA(r3_.x, r3_.y, r3_.z,  r2_.y, r2_.z, r2_.w, hs4);                \
    STEPA(r3_.w, r4_.x, r4_.y,  r1_.z, r1_.w, r2_.x, hs5);                \
    STEPA(r4_.z, r4_.w, r5_.x,  r0_.w, r1_.x, r1_.y, hs6);                \
    STEPA(r5_.y, r5_.z, r5_.w,  r0_.x, r0_.y, r0_.z, hs7); } while (0)

  // Store: slot i gets h(step i) fwd / h(step 7-i) bwd.
#define FLUSHA() do {                                                     \
    float sv0 = dirb ? hs7 : hs0, sv1 = dirb ? hs6 : hs1;                 \
    float sv2 = dirb ? hs5 : hs2, sv3 = dirb ? hs4 : hs3;                 \
    float sv4 = dirb ? hs3 : hs4, sv5 = dirb ? hs2 : hs5;                 \
    float sv6 = dirb ? hs1 : hs6, sv7 = dirb ? hs0 : hs7;                 \
    if ((lane & 7) < 3) {                                                 \
      float4* _o = (float4*)ywp;                                          \
      _o[0] = make_float4(sv0, sv1, sv2, sv3);                            \
      _o[1] = make_float4(sv4, sv5, sv6, sv7);                            \
    }                                                                     \
    ywp += ystep; } while (0)

  LDA(offA, p0, p1, p2, p3, p4, p5); offA += dstep;
  LDA(offB, q0, q1, q2, q3, q4, q5); offB += dstep;
  for (int it = 0; it < 32; ++it) {
    PROCA(p0, p1, p2, p3, p4, p5);
    FLUSHA();
    if (it < 31) { LDA(offA, p0, p1, p2, p3, p4, p5); offA += dstep; }
    PROCA(q0, q1, q2, q3, q4, q5);
    FLUSHA();
    if (it < 31) { LDA(offB, q0, q1, q2, q3, q4, q5); offB += dstep; }
  }
#undef LDA
#undef STEPA
#undef PROCA
#undef FLUSHA
}

// =================== Kernel B: layer-1 fwd + epilogue (8 lanes/batch) =======
__global__ __launch_bounds__(256, 1) void lstm_l1_fwd(
    const float* __restrict__ Wih1, const float* __restrict__ Whh1,
    const float* __restrict__ bih1, const float* __restrict__ bhh1,
    const float* __restrict__ Wih1r,
    const float* __restrict__ bih1r, const float* __restrict__ bhh1r,
    const float* __restrict__ Wlin, const float* __restrict__ blin,
    const float* __restrict__ y0f,   // [B][64][3][8]
    const float* __restrict__ y0b,   // [B][64][3][8]
    float* __restrict__ out)         // [B]
{
  int tid  = blockIdx.x * 256 + threadIdx.x;
  int b    = tid >> 3;
  int lane = tid & 7;
  bool qgo = (lane & 4) != 0;
  int j = lane & 3; int jj = (j < 3) ? j : 0;
  const int ra = (qgo ? 6 : 0) + jj, rb = ra + 3;
  const float kx = qgo ? (-2.f * LOG2E) : (-LOG2E);
  const float ky = -LOG2E;
  const float avx = qgo ? 2.f : 1.f;
  const float dvx = qgo ? -1.f : 0.f;

  // 6 input weights (cols 0-2: y0f, cols 3-5: y0b) + 3 recurrent + bias.
  v2f w0 = {Wih1[ra*6+0]*kx, Wih1[rb*6+0]*ky},
      w1 = {Wih1[ra*6+1]*kx, Wih1[rb*6+1]*ky},
      w2 = {Wih1[ra*6+2]*kx, Wih1[rb*6+2]*ky},
      w3 = {Wih1[ra*6+3]*kx, Wih1[rb*6+3]*ky},
      w4 = {Wih1[ra*6+4]*kx, Wih1[rb*6+4]*ky},
      w5 = {Wih1[ra*6+5]*kx, Wih1[rb*6+5]*ky};
  v2f u0 = {Whh1[ra*3+0]*kx, Whh1[rb*3+0]*ky},
      u1 = {Whh1[ra*3+1]*kx, Whh1[rb*3+1]*ky},
      u2 = {Whh1[ra*3+2]*kx, Whh1[rb*3+2]*ky};
  v2f b2 = {(bih1[ra]+bhh1[ra])*kx, (bih1[rb]+bhh1[rb])*ky};

  const float4* yfq = (const float4*)(y0f + (size_t)b * (T_ * 3));
  const float4* ybq = (const float4*)(y0b + (size_t)b * (T_ * 3));

  // Epilogue inputs y0(T-1): slot 511 = block 63, s=7, j-planes 0,8,16.
  const float* ufp = y0f + (size_t)b * (T_ * 3) + 63 * 24 + 7;
  const float* ubp = y0b + (size_t)b * (T_ * 3) + 63 * 24 + 7;
  float uf0 = ufp[0], uf1 = ufp[8], uf2 = ufp[16];
  float ub0 = ubp[0], ub1 = ubp[8], ub2 = ubp[16];

  float h = 0.f, c = 0.f, ha0 = 0.f, ha1 = 0.f, ha2 = 0.f;
  float hs0, hs1, hs2, hs3, hs4, hs5, hs6, hs7;  // unused sink (no store)
  float4 pf0, pf1, pf2, pf3, pf4, pf5, pb0, pb1, pb2, pb3, pb4, pb5;
  float4 qf0, qf1, qf2, qf3, qf4, qf5, qb0, qb1, qb2, qb3, qb4, qb5;

#define LDB(blk, F0,F1,F2,F3,F4,F5, G0,G1,G2,G3,G4,G5) do {               \
    const float4* _f = yfq + (blk) * 6;                                   \
    const float4* _g = ybq + (blk) * 6;                                   \
    F0 = _f[0]; F1 = _f[1]; F2 = _f[2];                                   \
    F3 = _f[3]; F4 = _f[4]; F5 = _f[5];                                   \
    G0 = _g[0]; G1 = _g[1]; G2 = _g[2];                                   \
    G3 = _g[3]; G4 = _g[4]; G5 = _g[5];                                   \
    __builtin_amdgcn_sched_barrier(0); } while (0)

#define STEPB(f0, f1, f2, g0, g1, g2, HOUT) do {                          \
    v2f pv = pkfma(w0, (f0), b2); pv = pkfma(w1, (f1), pv);               \
    pv = pkfma(w2, (f2), pv);                                             \
    v2f nv = w3 * sp(g0); nv = pkfma(w4, (g1), nv);                       \
    nv = pkfma(w5, (g2), nv);                                             \
    v2f uv = u0 * sp(ha0); uv = pkfma(u1, ha1, uv);                       \
    uv = pkfma(u2, ha2, uv);                                              \
    pv = (pv + nv) + uv;                                                  \
    CELL_TAIL(HOUT) } while (0)

  // block layout [3 j][8 s]: f_j(s) = el(j*8+s)
#define PROCB(F0,F1,F2,F3,F4,F5, G0,G1,G2,G3,G4,G5) do {                  \
    STEPB(F0.x, F2.x, F4.x,  G0.x, G2.x, G4.x, hs0);                      \
    STEPB(F0.y, F2.y, F4.y,  G0.y, G2.y, G4.y, hs1);                      \
    STEPB(F0.z, F2.z, F4.z,  G0.z, G2.z, G4.z, hs2);                      \
    STEPB(F0.w, F2.w, F4.w,  G0.w, G2.w, G4.w, hs3);                      \
    STEPB(F1.x, F3.x, F5.x,  G1.x, G3.x, G5.x, hs4);                      \
    STEPB(F1.y, F3.y, F5.y,  G1.y, G3.y, G5.y, hs5);                      \
    STEPB(F1.z, F3.z, F5.z,  G1.z, G3.z, G5.z, hs6);                      \
    STEPB(F1.w, F3.w, F5.w,  G1.w, G3.w, G5.w, hs7); } while (0)

  LDB(0, pf0,pf1,pf2,pf3,pf4,pf5, pb0,pb1,pb2,pb3,pb4,pb5);
  LDB(1, qf0,qf1,qf2,qf3,qf4,qf5, qb0,qb1,qb2,qb3,qb4,qb5);
  for (int it = 0; it < 32; ++it) {
    PROCB(pf0,pf1,pf2,pf3,pf4,pf5, pb0,pb1,pb2,pb3,pb4,pb5);
    if (it < 31) LDB(2*it+2, pf0,pf1,pf2,pf3,pf4,pf5, pb0,pb1,pb2,pb3,pb4,pb5);
    PROCB(qf0,qf1,qf2,qf3,qf4,qf5, qb0,qb1,qb2,qb3,qb4,qb5);
    if (it < 31) LDB(2*it+3, qf0,qf1,qf2,qf3,qf4,qf5, qb0,qb1,qb2,qb3,qb4,qb5);
  }
  (void)hs0; (void)hs1; (void)hs2; (void)hs3;
  (void)hs4; (void)hs5; (void)hs6; (void)hs7;
  // h = h1_fwd[j](T-1) on all lanes (both quads redundant).

  // Layer-1 backward: one gate-split step from zero state on y0(T-1).
  float h1b;
  {
    v2f r0 = {Wih1r[ra*6+0]*kx, Wih1r[rb*6+0]*ky},
        r1 = {Wih1r[ra*6+1]*kx, Wih1r[rb*6+1]*ky},
        r2 = {Wih1r[ra*6+2]*kx, Wih1r[rb*6+2]*ky},
        r3 = {Wih1r[ra*6+3]*kx, Wih1r[rb*6+3]*ky},
        r4 = {Wih1r[ra*6+4]*kx, Wih1r[rb*6+4]*ky},
        r5 = {Wih1r[ra*6+5]*kx, Wih1r[rb*6+5]*ky};
    v2f br = {(bih1r[ra]+bhh1r[ra])*kx, (bih1r[rb]+bhh1r[rb])*ky};
    v2f qv = pkfma(r0, uf0, br); qv = pkfma(r1, uf1, qv);
    qv = pkfma(r2, uf2, qv);     qv = pkfma(r3, ub0, qv);
    qv = pkfma(r4, ub1, qv);     qv = pkfma(r5, ub2, qv);
    float r0v = act_(qv.x);
    float ayv = act_(qv.y);
    float axv = __builtin_fmaf(avx, r0v, dvx);
    float slx = dppf<SHL4>(axv), sly = dppf<SHL4>(ayv);
    float srx = dppf<SHR4>(axv);
    float gi = qgo ? srx : axv;
    float gG = qgo ? axv : slx;
    float gO = qgo ? ayv : sly;
    float cb = gi * gG;              // c_prev = 0 -> f-gate drops out
    h1b = gO * tanh_(cb);
  }

  // out[b] = sigmoid(Wlin[0:3].h1f + Wlin[3:6].h1b + blin)
  float part = 0.f;
  if (!qgo && j < 3) part = __builtin_fmaf(Wlin[j], h, Wlin[3 + j] * h1b);
  part += __shfl_xor(part, 1, 8);
  part += __shfl_xor(part, 2, 8);
  part += __shfl_xor(part, 4, 8);
  if (lane == 0) out[b] = sigm_(part + blin[0]);
#undef LDB
#undef STEPB
#undef PROCB
}

extern "C" void kernel_launch(void* const* d_in, const int* in_sizes, int n_in,
                              void* d_out, int out_size, void* d_ws, size_t ws_size,
                              hipStream_t stream) {
  const float* x        = (const float*)d_in[0];
  const float* W_ih_l0  = (const float*)d_in[1];
  const float* W_hh_l0  = (const float*)d_in[2];
  const float* b_ih_l0  = (const float*)d_in[3];
  const float* b_hh_l0  = (const float*)d_in[4];
  const float* W_ih_l0r = (const float*)d_in[5];
  const float* W_hh_l0r = (const float*)d_in[6];
  const float* b_ih_l0r = (const float*)d_in[7];
  const float* b_hh_l0r = (const float*)d_in[8];
  const float* W_ih_l1  = (const float*)d_in[9];
  const float* W_hh_l1  = (const float*)d_in[10];
  const float* b_ih_l1  = (const float*)d_in[11];
  const float* b_hh_l1  = (const float*)d_in[12];
  const float* W_ih_l1r = (const float*)d_in[13];
  const float* b_ih_l1r = (const float*)d_in[15];
  const float* b_hh_l1r = (const float*)d_in[16];
  const float* W_lin    = (const float*)d_in[17];
  const float* b_lin    = (const float*)d_in[18];

  float* y0f = (float*)d_ws;                    // 48 MB
  float* y0b = (float*)d_ws + (size_t)B_ * T_ * 3;  // 48 MB
  float* out = (float*)d_out;

  // KA: 16 lanes/batch -> 131072 threads = 2048 waves (2 waves/SIMD)
  lstm_l0_both<<<(B_ * 16) / 256, 256, 0, stream>>>(
      x, W_ih_l0, W_hh_l0, b_ih_l0, b_hh_l0,
      W_ih_l0r, W_hh_l0r, b_ih_l0r, b_hh_l0r, y0f, y0b);

  // KB: 8 lanes/batch -> 65536 threads = 1024 waves (1 wave/SIMD)
  lstm_l1_fwd<<<(B_ * 8) / 256, 256, 0, stream>>>(
      W_ih_l1, W_hh_l1, b_ih_l1, b_hh_l1,
      W_ih_l1r, b_ih_l1r, b_hh_l1r,
      W_lin, b_lin, y0f, y0b, out);
}

// Round 10
// 151.859 us; speedup vs baseline: 1.1381x; 1.1381x over previous
//
#include <hip/hip_runtime.h>

// Model_47510928228872: 2-layer bidirectional LSTM (H=3) + linear + sigmoid.
// B=8192, T=512, fp32.
//
// Round 10: packed fp32 on CDNA4 is HALF-RATE (157.3 TF = scalar-FMA rate;
// v_pk_fma_f32 = 4cy issue) -> packed gate math saved nothing. Rewrite KA as
// a pure-scalar 4-lane cell: lane j owns hidden j (all 4 gate rows), weights
// prescaled into VGPRs, quad_perm h-broadcast, x distributed across the quad
// (float4+float2 per lane) and extracted via compile-time quad_perm.
// Direction (l0-fwd / l0-bwd) = wave-uniform blockIdx split, template<DIRB>.
//   KA: 1024 waves (1/SIMD), ~122 issue-cy/step, 16 batches/wave.
//   KB: round-9 l1-fwd kernel unchanged (proven).
// y0f/y0b layout [B][64 blk][3 j][8 s], slot t = h(t).

#define B_ 8192
#define T_ 512
#define LOG2E 1.4426950408889634f

typedef float v2f __attribute__((ext_vector_type(2)));

__device__ __forceinline__ float rcp_(float x)  { return __builtin_amdgcn_rcpf(x); }
__device__ __forceinline__ float exp2_(float x) { return __builtin_amdgcn_exp2f(x); }
__device__ __forceinline__ float sigm_(float x) {
  return rcp_(1.0f + exp2_(-LOG2E * x));
}
__device__ __forceinline__ float tanh_(float x) {
  return 1.0f - 2.0f * rcp_(1.0f + exp2_(2.0f * LOG2E * x));
}
__device__ __forceinline__ float act_(float p) { return rcp_(1.f + exp2_(p)); }

__device__ __forceinline__ v2f sp(float s) { return (v2f){s, s}; }
__device__ __forceinline__ v2f pkfma(v2f a, float b, v2f c) {
  return __builtin_elementwise_fma(a, sp(b), c);
}

template <int CTRL>
__device__ __forceinline__ float dppf(float v) {
  int s = __float_as_int(v);
  return __int_as_float(__builtin_amdgcn_update_dpp(s, s, CTRL, 0xF, 0xF, false));
}
#define QP0 dppf<0x00>
#define QP1 dppf<0x55>
#define QP2 dppf<0xAA>
#define QP3 dppf<0xFF>
#define SHL4 0x104
#define SHR4 0x114

// ===================== Kernel A: layer-0 fwd+bwd, scalar 4-lane =============
// Lane l (=jl) of each quad: owns hidden j=min(jl,2)->jj (lane 3 dups j=0).
// x block (24 dwords = 8 steps): lane l holds float4 A=dw[4l..4l+3] and
// float2 B=dw[16+2l..17+2l]; per-step operands via compile-time quad_perm.

template <bool DIRB>
__device__ __forceinline__ void l0_run(
    const float* __restrict__ x,
    const float* __restrict__ Wi, const float* __restrict__ Wh,
    const float* __restrict__ bi, const float* __restrict__ bh,
    float* __restrict__ yout, int b, int jl)
{
  const int jj = (jl < 3) ? jl : 0;
  const int ri = jj, rf = 3 + jj, rg = 6 + jj, ro = 9 + jj;
  const float sL = -LOG2E, sG = -2.f * LOG2E;

  // Prescaled per-lane weights (VGPR scalars).
  float wi_i0 = Wi[ri*3+0]*sL, wi_i1 = Wi[ri*3+1]*sL, wi_i2 = Wi[ri*3+2]*sL;
  float wi_f0 = Wi[rf*3+0]*sL, wi_f1 = Wi[rf*3+1]*sL, wi_f2 = Wi[rf*3+2]*sL;
  float wi_g0 = Wi[rg*3+0]*sG, wi_g1 = Wi[rg*3+1]*sG, wi_g2 = Wi[rg*3+2]*sG;
  float wi_o0 = Wi[ro*3+0]*sL, wi_o1 = Wi[ro*3+1]*sL, wi_o2 = Wi[ro*3+2]*sL;
  float wh_i0 = Wh[ri*3+0]*sL, wh_i1 = Wh[ri*3+1]*sL, wh_i2 = Wh[ri*3+2]*sL;
  float wh_f0 = Wh[rf*3+0]*sL, wh_f1 = Wh[rf*3+1]*sL, wh_f2 = Wh[rf*3+2]*sL;
  float wh_g0 = Wh[rg*3+0]*sG, wh_g1 = Wh[rg*3+1]*sG, wh_g2 = Wh[rg*3+2]*sG;
  float wh_o0 = Wh[ro*3+0]*sL, wh_o1 = Wh[ro*3+1]*sL, wh_o2 = Wh[ro*3+2]*sL;
  float b_i = (bi[ri]+bh[ri])*sL, b_f = (bi[rf]+bh[rf])*sL;
  float b_g = (bi[rg]+bh[rg])*sG, b_o = (bi[ro]+bh[ro])*sL;

  float h = 0.f, c = 0.f, ha0 = 0.f, ha1 = 0.f, ha2 = 0.f;
  float hs0, hs1, hs2, hs3, hs4, hs5, hs6, hs7;

  const float*  xrow = x + (size_t)b * (T_ * 3);
  const float4* xq4  = (const float4*)xrow;          // f4 idx: blk*6 + jl
  const float2* xq2  = (const float2*)(xrow);        // f2 idx: blk*12 + 8 + jl
  float* ybase = yout + (size_t)b * (T_ * 3) + jj * 8;

  float4 pA; float2 pB; float4 qA; float2 qB;

#define LDQ(blk, A_, B_) do {                                             \
    A_ = xq4[(blk) * 6 + jl];                                             \
    B_ = xq2[(blk) * 12 + 8 + jl];                                        \
    __builtin_amdgcn_sched_barrier(0); } while (0)

#define STEPS(X0, X1, X2, HOUT) do {                                      \
    float _x0 = (X0), _x1 = (X1), _x2 = (X2);                             \
    float _pi = __builtin_fmaf(wi_i0, _x0, b_i);                          \
    _pi = __builtin_fmaf(wi_i1, _x1, _pi);                                \
    _pi = __builtin_fmaf(wi_i2, _x2, _pi);                                \
    float _qi = wh_i0 * ha0;                                              \
    _qi = __builtin_fmaf(wh_i1, ha1, _qi);                                \
    _qi = __builtin_fmaf(wh_i2, ha2, _qi);                                \
    float _pf = __builtin_fmaf(wi_f0, _x0, b_f);                          \
    _pf = __builtin_fmaf(wi_f1, _x1, _pf);                                \
    _pf = __builtin_fmaf(wi_f2, _x2, _pf);                                \
    float _qf = wh_f0 * ha0;                                              \
    _qf = __builtin_fmaf(wh_f1, ha1, _qf);                                \
    _qf = __builtin_fmaf(wh_f2, ha2, _qf);                                \
    float _pg = __builtin_fmaf(wi_g0, _x0, b_g);                          \
    _pg = __builtin_fmaf(wi_g1, _x1, _pg);                                \
    _pg = __builtin_fmaf(wi_g2, _x2, _pg);                                \
    float _qg = wh_g0 * ha0;                                              \
    _qg = __builtin_fmaf(wh_g1, ha1, _qg);                                \
    _qg = __builtin_fmaf(wh_g2, ha2, _qg);                                \
    float _po = __builtin_fmaf(wi_o0, _x0, b_o);                          \
    _po = __builtin_fmaf(wi_o1, _x1, _po);                                \
    _po = __builtin_fmaf(wi_o2, _x2, _po);                                \
    float _qo = wh_o0 * ha0;                                              \
    _qo = __builtin_fmaf(wh_o1, ha1, _qo);                                \
    _qo = __builtin_fmaf(wh_o2, ha2, _qo);                                \
    float _ig = act_(_pi + _qi);                                          \
    float _fg = act_(_pf + _qf);                                          \
    float _gg = __builtin_fmaf(2.f, act_(_pg + _qg), -1.f);               \
    float _og = act_(_po + _qo);                                          \
    c = __builtin_fmaf(_fg, c, _ig * _gg);                                \
    float _th = __builtin_fmaf(                                           \
        2.f, rcp_(1.f + exp2_(-2.f * LOG2E * c)), -1.f);                  \
    h = _og * _th;                                                        \
    ha0 = QP0(h); ha1 = QP1(h); ha2 = QP2(h);                             \
    HOUT = h; } while (0)

  // step s of a block: x dwords 3s..3s+2; dw d<16 -> lane d>>2, comp d&3;
  // d>=16 -> lane (d-16)>>1, comp (d-16)&1. quad_perm pulls from that lane.
#define S0(A_, B_) STEPS(QP0(A_.x), QP0(A_.y), QP0(A_.z), hs0)
#define S1(A_, B_) STEPS(QP0(A_.w), QP1(A_.x), QP1(A_.y), hs1)
#define S2(A_, B_) STEPS(QP1(A_.z), QP1(A_.w), QP2(A_.x), hs2)
#define S3(A_, B_) STEPS(QP2(A_.y), QP2(A_.z), QP2(A_.w), hs3)
#define S4(A_, B_) STEPS(QP3(A_.x), QP3(A_.y), QP3(A_.z), hs4)
#define S5(A_, B_) STEPS(QP3(A_.w), QP0(B_.x), QP0(B_.y), hs5)
#define S6(A_, B_) STEPS(QP1(B_.x), QP1(B_.y), QP2(B_.x), hs6)
#define S7(A_, B_) STEPS(QP2(B_.y), QP3(B_.x), QP3(B_.y), hs7)

#define PROCQ(A_, B_) do {                                                \
    if (DIRB) { S7(A_,B_); S6(A_,B_); S5(A_,B_); S4(A_,B_);               \
                S3(A_,B_); S2(A_,B_); S1(A_,B_); S0(A_,B_); }             \
    else      { S0(A_,B_); S1(A_,B_); S2(A_,B_); S3(A_,B_);               \
                S4(A_,B_); S5(A_,B_); S6(A_,B_); S7(A_,B_); } } while (0)

#define STQ(blk) do {                                                     \
    if (jl < 3) {                                                         \
      float4* _o = (float4*)(ybase + (blk) * 24);                         \
      _o[0] = make_float4(hs0, hs1, hs2, hs3);                            \
      _o[1] = make_float4(hs4, hs5, hs6, hs7);                            \
    } } while (0)

#define BLK(k) (DIRB ? (63 - (k)) : (k))

  LDQ(BLK(0), pA, pB);
  LDQ(BLK(1), qA, qB);
  for (int k = 0; k < 64; k += 2) {
    PROCQ(pA, pB);
    STQ(BLK(k));
    if (k + 2 < 64) LDQ(BLK(k + 2), pA, pB);
    PROCQ(qA, qB);
    STQ(BLK(k + 1));
    if (k + 3 < 64) LDQ(BLK(k + 3), qA, qB);
  }
#undef LDQ
#undef STEPS
#undef S0
#undef S1
#undef S2
#undef S3
#undef S4
#undef S5
#undef S6
#undef S7
#undef PROCQ
#undef STQ
#undef BLK
}

__global__ __launch_bounds__(256, 2) void lstm_l0_scalar(
    const float* __restrict__ x,
    const float* __restrict__ Wf_ih, const float* __restrict__ Wf_hh,
    const float* __restrict__ bf_ih, const float* __restrict__ bf_hh,
    const float* __restrict__ Wr_ih, const float* __restrict__ Wr_hh,
    const float* __restrict__ br_ih, const float* __restrict__ br_hh,
    float* __restrict__ y0f, float* __restrict__ y0b)
{
  int gid = blockIdx.x * 256 + threadIdx.x;
  const int nfwd = B_ * 4;             // multiple of 256 -> wave-uniform split
  if (gid < nfwd) {
    int b = gid >> 2, jl = gid & 3;
    l0_run<false>(x, Wf_ih, Wf_hh, bf_ih, bf_hh, y0f, b, jl);
  } else {
    int g2 = gid - nfwd;
    int b = g2 >> 2, jl = g2 & 3;
    l0_run<true>(x, Wr_ih, Wr_hh, br_ih, br_hh, y0b, b, jl);
  }
}

// ======= Kernel B: layer-1 fwd + epilogue (round-9 version, unchanged) ======
#define CELL_TAIL(HOUT)                                                   \
    float r0v = act_(pv.x);                                               \
    float ayv = act_(pv.y);                                               \
    float axv = __builtin_fmaf(avx, r0v, dvx);                            \
    float slx = dppf<SHL4>(axv), sly = dppf<SHL4>(ayv);                   \
    float srx = dppf<SHR4>(axv), sry = dppf<SHR4>(ayv);                   \
    float pig = axv * (qgo ? srx : slx);                                  \
    float gf  = qgo ? sry : ayv;                                          \
    float gO  = qgo ? ayv : sly;                                          \
    c = __builtin_fmaf(gf, c, pig);                                       \
    float th = __builtin_fmaf(                                            \
        2.f, rcp_(1.f + exp2_(-2.f * LOG2E * c)), -1.f);                  \
    h = gO * th;                                                          \
    ha0 = QP0(h); ha1 = QP1(h); ha2 = QP2(h);                             \
    HOUT = h;

__global__ __launch_bounds__(256, 1) void lstm_l1_fwd(
    const float* __restrict__ Wih1, const float* __restrict__ Whh1,
    const float* __restrict__ bih1, const float* __restrict__ bhh1,
    const float* __restrict__ Wih1r,
    const float* __restrict__ bih1r, const float* __restrict__ bhh1r,
    const float* __restrict__ Wlin, const float* __restrict__ blin,
    const float* __restrict__ y0f, const float* __restrict__ y0b,
    float* __restrict__ out)
{
  int tid  = blockIdx.x * 256 + threadIdx.x;
  int b    = tid >> 3;
  int lane = tid & 7;
  bool qgo = (lane & 4) != 0;
  int j = lane & 3; int jj = (j < 3) ? j : 0;
  const int ra = (qgo ? 6 : 0) + jj, rb = ra + 3;
  const float kx = qgo ? (-2.f * LOG2E) : (-LOG2E);
  const float ky = -LOG2E;
  const float avx = qgo ? 2.f : 1.f;
  const float dvx = qgo ? -1.f : 0.f;

  v2f w0 = {Wih1[ra*6+0]*kx, Wih1[rb*6+0]*ky},
      w1 = {Wih1[ra*6+1]*kx, Wih1[rb*6+1]*ky},
      w2 = {Wih1[ra*6+2]*kx, Wih1[rb*6+2]*ky},
      w3 = {Wih1[ra*6+3]*kx, Wih1[rb*6+3]*ky},
      w4 = {Wih1[ra*6+4]*kx, Wih1[rb*6+4]*ky},
      w5 = {Wih1[ra*6+5]*kx, Wih1[rb*6+5]*ky};
  v2f u0 = {Whh1[ra*3+0]*kx, Whh1[rb*3+0]*ky},
      u1 = {Whh1[ra*3+1]*kx, Whh1[rb*3+1]*ky},
      u2 = {Whh1[ra*3+2]*kx, Whh1[rb*3+2]*ky};
  v2f b2 = {(bih1[ra]+bhh1[ra])*kx, (bih1[rb]+bhh1[rb])*ky};

  const float4* yfq = (const float4*)(y0f + (size_t)b * (T_ * 3));
  const float4* ybq = (const float4*)(y0b + (size_t)b * (T_ * 3));

  const float* ufp = y0f + (size_t)b * (T_ * 3) + 63 * 24 + 7;
  const float* ubp = y0b + (size_t)b * (T_ * 3) + 63 * 24 + 7;
  float uf0 = ufp[0], uf1 = ufp[8], uf2 = ufp[16];
  float ub0 = ubp[0], ub1 = ubp[8], ub2 = ubp[16];

  float h = 0.f, c = 0.f, ha0 = 0.f, ha1 = 0.f, ha2 = 0.f;
  float hs0, hs1, hs2, hs3, hs4, hs5, hs6, hs7;
  float4 pf0, pf1, pf2, pf3, pf4, pf5, pb0, pb1, pb2, pb3, pb4, pb5;
  float4 qf0, qf1, qf2, qf3, qf4, qf5, qb0, qb1, qb2, qb3, qb4, qb5;

#define LDB(blk, F0,F1,F2,F3,F4,F5, G0,G1,G2,G3,G4,G5) do {               \
    const float4* _f = yfq + (blk) * 6;                                   \
    const float4* _g = ybq + (blk) * 6;                                   \
    F0 = _f[0]; F1 = _f[1]; F2 = _f[2];                                   \
    F3 = _f[3]; F4 = _f[4]; F5 = _f[5];                                   \
    G0 = _g[0]; G1 = _g[1]; G2 = _g[2];                                   \
    G3 = _g[3]; G4 = _g[4]; G5 = _g[5];                                   \
    __builtin_amdgcn_sched_barrier(0); } while (0)

#define STEPB(f0, f1, f2, g0, g1, g2, HOUT) do {                          \
    v2f pv = pkfma(w0, (f0), b2); pv = pkfma(w1, (f1), pv);               \
    pv = pkfma(w2, (f2), pv);                                             \
    v2f nv = w3 * sp(g0); nv = pkfma(w4, (g1), nv);                       \
    nv = pkfma(w5, (g2), nv);                                             \
    v2f uv = u0 * sp(ha0); uv = pkfma(u1, ha1, uv);                       \
    uv = pkfma(u2, ha2, uv);                                              \
    pv = (pv + nv) + uv;                                                  \
    CELL_TAIL(HOUT) } while (0)

#define PROCB(F0,F1,F2,F3,F4,F5, G0,G1,G2,G3,G4,G5) do {                  \
    STEPB(F0.x, F2.x, F4.x,  G0.x, G2.x, G4.x, hs0);                      \
    STEPB(F0.y, F2.y, F4.y,  G0.y, G2.y, G4.y, hs1);                      \
    STEPB(F0.z, F2.z, F4.z,  G0.z, G2.z, G4.z, hs2);                      \
    STEPB(F0.w, F2.w, F4.w,  G0.w, G2.w, G4.w, hs3);                      \
    STEPB(F1.x, F3.x, F5.x,  G1.x, G3.x, G5.x, hs4);                      \
    STEPB(F1.y, F3.y, F5.y,  G1.y, G3.y, G5.y, hs5);                      \
    STEPB(F1.z, F3.z, F5.z,  G1.z, G3.z, G5.z, hs6);                      \
    STEPB(F1.w, F3.w, F5.w,  G1.w, G3.w, G5.w, hs7); } while (0)

  LDB(0, pf0,pf1,pf2,pf3,pf4,pf5, pb0,pb1,pb2,pb3,pb4,pb5);
  LDB(1, qf0,qf1,qf2,qf3,qf4,qf5, qb0,qb1,qb2,qb3,qb4,qb5);
  for (int it = 0; it < 32; ++it) {
    PROCB(pf0,pf1,pf2,pf3,pf4,pf5, pb0,pb1,pb2,pb3,pb4,pb5);
    if (it < 31) LDB(2*it+2, pf0,pf1,pf2,pf3,pf4,pf5, pb0,pb1,pb2,pb3,pb4,pb5);
    PROCB(qf0,qf1,qf2,qf3,qf4,qf5, qb0,qb1,qb2,qb3,qb4,qb5);
    if (it < 31) LDB(2*it+3, qf0,qf1,qf2,qf3,qf4,qf5, qb0,qb1,qb2,qb3,qb4,qb5);
  }
  (void)hs0; (void)hs1; (void)hs2; (void)hs3;
  (void)hs4; (void)hs5; (void)hs6; (void)hs7;

  float h1b;
  {
    v2f r0 = {Wih1r[ra*6+0]*kx, Wih1r[rb*6+0]*ky},
        r1 = {Wih1r[ra*6+1]*kx, Wih1r[rb*6+1]*ky},
        r2 = {Wih1r[ra*6+2]*kx, Wih1r[rb*6+2]*ky},
        r3 = {Wih1r[ra*6+3]*kx, Wih1r[rb*6+3]*ky},
        r4 = {Wih1r[ra*6+4]*kx, Wih1r[rb*6+4]*ky},
        r5 = {Wih1r[ra*6+5]*kx, Wih1r[rb*6+5]*ky};
    v2f br = {(bih1r[ra]+bhh1r[ra])*kx, (bih1r[rb]+bhh1r[rb])*ky};
    v2f qv = pkfma(r0, uf0, br); qv = pkfma(r1, uf1, qv);
    qv = pkfma(r2, uf2, qv);     qv = pkfma(r3, ub0, qv);
    qv = pkfma(r4, ub1, qv);     qv = pkfma(r5, ub2, qv);
    float r0v = act_(qv.x);
    float ayv = act_(qv.y);
    float axv = __builtin_fmaf(avx, r0v, dvx);
    float slx = dppf<SHL4>(axv), sly = dppf<SHL4>(ayv);
    float srx = dppf<SHR4>(axv);
    float gi = qgo ? srx : axv;
    float gG = qgo ? axv : slx;
    float gO = qgo ? ayv : sly;
    float cb = gi * gG;
    h1b = gO * tanh_(cb);
  }

  float part = 0.f;
  if (!qgo && j < 3) part = __builtin_fmaf(Wlin[j], h, Wlin[3 + j] * h1b);
  part += __shfl_xor(part, 1, 8);
  part += __shfl_xor(part, 2, 8);
  part += __shfl_xor(part, 4, 8);
  if (lane == 0) out[b] = sigm_(part + blin[0]);
#undef LDB
#undef STEPB
#undef PROCB
}

extern "C" void kernel_launch(void* const* d_in, const int* in_sizes, int n_in,
                              void* d_out, int out_size, void* d_ws, size_t ws_size,
                              hipStream_t stream) {
  const float* x        = (const float*)d_in[0];
  const float* W_ih_l0  = (const float*)d_in[1];
  const float* W_hh_l0  = (const float*)d_in[2];
  const float* b_ih_l0  = (const float*)d_in[3];
  const float* b_hh_l0  = (const float*)d_in[4];
  const float* W_ih_l0r = (const float*)d_in[5];
  const float* W_hh_l0r = (const float*)d_in[6];
  const float* b_ih_l0r = (const float*)d_in[7];
  const float* b_hh_l0r = (const float*)d_in[8];
  const float* W_ih_l1  = (const float*)d_in[9];
  const float* W_hh_l1  = (const float*)d_in[10];
  const float* b_ih_l1  = (const float*)d_in[11];
  const float* b_hh_l1  = (const float*)d_in[12];
  const float* W_ih_l1r = (const float*)d_in[13];
  const float* b_ih_l1r = (const float*)d_in[15];
  const float* b_hh_l1r = (const float*)d_in[16];
  const float* W_lin    = (const float*)d_in[17];
  const float* b_lin    = (const float*)d_in[18];

  float* y0f = (float*)d_ws;                        // 48 MB
  float* y0b = (float*)d_ws + (size_t)B_ * T_ * 3;  // 48 MB
  float* out = (float*)d_out;

  // KA: fwd (32768 threads) + bwd (32768 threads) in one launch = 1024 waves
  lstm_l0_scalar<<<(B_ * 4 * 2) / 256, 256, 0, stream>>>(
      x, W_ih_l0, W_hh_l0, b_ih_l0, b_hh_l0,
      W_ih_l0r, W_hh_l0r, b_ih_l0r, b_hh_l0r, y0f, y0b);

  // KB: 8 lanes/batch -> 1024 waves
  lstm_l1_fwd<<<(B_ * 8) / 256, 256, 0, stream>>>(
      W_ih_l1, W_hh_l1, b_ih_l1, b_hh_l1,
      W_ih_l1r, b_ih_l1r, b_hh_l1r,
      W_lin, b_lin, y0f, y0b, out);
}

// Round 11
// 145.908 us; speedup vs baseline: 1.1845x; 1.0408x over previous
//
#include <hip/hip_runtime.h>

// Model_47510928228872: 2-layer bidirectional LSTM (H=3) + linear + sigmoid.
// B=8192, T=512, fp32.
//
// Round 11: VGPR_Count=40 revealed the compiler re-loads "loop-invariant"
// weights inside the t-loop (live-range split) -> VMEM+vmcnt stalls every
// block. Fix: PIN loop invariants as inline-asm-defined values (opaque to
// remat; allocator must keep them in VGPRs). KA lanes also keep a FULL
// per-lane copy of each 24-dword x block (quad lanes load same addresses,
// L1 broadcast) -> no per-step extraction DPPs.
//  KA: l0-fwd + l0-bwd, scalar 4-lane cell, one launch (wave-uniform split),
//      1024 waves. KB: l1-fwd gate-split 8-lane (round-9) + pins.
// y0f/y0b layout [B][64 blk][3 j][8 s], slot t = h(t).

#define B_ 8192
#define T_ 512
#define LOG2E 1.4426950408889634f

typedef float v2f __attribute__((ext_vector_type(2)));

__device__ __forceinline__ float rcp_(float x)  { return __builtin_amdgcn_rcpf(x); }
__device__ __forceinline__ float exp2_(float x) { return __builtin_amdgcn_exp2f(x); }
__device__ __forceinline__ float sigm_(float x) {
  return rcp_(1.0f + exp2_(-LOG2E * x));
}
__device__ __forceinline__ float tanh_(float x) {
  return 1.0f - 2.0f * rcp_(1.0f + exp2_(2.0f * LOG2E * x));
}
__device__ __forceinline__ float act_(float p) { return rcp_(1.f + exp2_(p)); }

__device__ __forceinline__ v2f sp(float s) { return (v2f){s, s}; }
__device__ __forceinline__ v2f pkfma(v2f a, float b, v2f c) {
  return __builtin_elementwise_fma(a, sp(b), c);
}

// Pin a value: defined by opaque asm -> cannot be rematerialized/reloaded.
#define PIN1(v) asm volatile("" : "+v"(v))
#define PIN2(v) do {                                                      \
    double _d = __builtin_bit_cast(double, v);                            \
    asm volatile("" : "+v"(_d));                                          \
    v = __builtin_bit_cast(v2f, _d); } while (0)

template <int CTRL>
__device__ __forceinline__ float dppf(float v) {
  int s = __float_as_int(v);
  return __int_as_float(__builtin_amdgcn_update_dpp(s, s, CTRL, 0xF, 0xF, false));
}
#define QP0 dppf<0x00>
#define QP1 dppf<0x55>
#define QP2 dppf<0xAA>
#define SHL4 0x104
#define SHR4 0x114

// ===================== Kernel A: layer-0 fwd+bwd, scalar 4-lane =============
template <bool DIRB>
__device__ __forceinline__ void l0_run(
    const float* __restrict__ x,
    const float* __restrict__ Wi, const float* __restrict__ Wh,
    const float* __restrict__ bi, const float* __restrict__ bh,
    float* __restrict__ yout, int b, int jl)
{
  const int jj = (jl < 3) ? jl : 0;
  const int ri = jj, rf = 3 + jj, rg = 6 + jj, ro = 9 + jj;
  const float sL = -LOG2E, sG = -2.f * LOG2E;

  float wi_i0 = Wi[ri*3+0]*sL, wi_i1 = Wi[ri*3+1]*sL, wi_i2 = Wi[ri*3+2]*sL;
  float wi_f0 = Wi[rf*3+0]*sL, wi_f1 = Wi[rf*3+1]*sL, wi_f2 = Wi[rf*3+2]*sL;
  float wi_g0 = Wi[rg*3+0]*sG, wi_g1 = Wi[rg*3+1]*sG, wi_g2 = Wi[rg*3+2]*sG;
  float wi_o0 = Wi[ro*3+0]*sL, wi_o1 = Wi[ro*3+1]*sL, wi_o2 = Wi[ro*3+2]*sL;
  float wh_i0 = Wh[ri*3+0]*sL, wh_i1 = Wh[ri*3+1]*sL, wh_i2 = Wh[ri*3+2]*sL;
  float wh_f0 = Wh[rf*3+0]*sL, wh_f1 = Wh[rf*3+1]*sL, wh_f2 = Wh[rf*3+2]*sL;
  float wh_g0 = Wh[rg*3+0]*sG, wh_g1 = Wh[rg*3+1]*sG, wh_g2 = Wh[rg*3+2]*sG;
  float wh_o0 = Wh[ro*3+0]*sL, wh_o1 = Wh[ro*3+1]*sL, wh_o2 = Wh[ro*3+2]*sL;
  float b_i = (bi[ri]+bh[ri])*sL, b_f = (bi[rf]+bh[rf])*sL;
  float b_g = (bi[rg]+bh[rg])*sG, b_o = (bi[ro]+bh[ro])*sL;

  PIN1(wi_i0); PIN1(wi_i1); PIN1(wi_i2);
  PIN1(wi_f0); PIN1(wi_f1); PIN1(wi_f2);
  PIN1(wi_g0); PIN1(wi_g1); PIN1(wi_g2);
  PIN1(wi_o0); PIN1(wi_o1); PIN1(wi_o2);
  PIN1(wh_i0); PIN1(wh_i1); PIN1(wh_i2);
  PIN1(wh_f0); PIN1(wh_f1); PIN1(wh_f2);
  PIN1(wh_g0); PIN1(wh_g1); PIN1(wh_g2);
  PIN1(wh_o0); PIN1(wh_o1); PIN1(wh_o2);
  PIN1(b_i); PIN1(b_f); PIN1(b_g); PIN1(b_o);

  float h = 0.f, c = 0.f, ha0 = 0.f, ha1 = 0.f, ha2 = 0.f;
  float hs0, hs1, hs2, hs3, hs4, hs5, hs6, hs7;

  const float4* xq4 = (const float4*)(x + (size_t)b * (T_ * 3));
  float* ybase = yout + (size_t)b * (T_ * 3) + jj * 8;

  float4 p0, p1, p2, p3, p4, p5, q0, q1, q2, q3, q4, q5;

#define LDQ(blk, R0, R1, R2, R3, R4, R5) do {                             \
    const float4* _p = xq4 + (blk) * 6;                                   \
    R0 = _p[0]; R1 = _p[1]; R2 = _p[2];                                   \
    R3 = _p[3]; R4 = _p[4]; R5 = _p[5];                                   \
    __builtin_amdgcn_sched_barrier(0); } while (0)

#define STEPS(X0, X1, X2, HOUT) do {                                      \
    float _x0 = (X0), _x1 = (X1), _x2 = (X2);                             \
    float _pi = __builtin_fmaf(wi_i0, _x0, b_i);                          \
    _pi = __builtin_fmaf(wi_i1, _x1, _pi);                                \
    _pi = __builtin_fmaf(wi_i2, _x2, _pi);                                \
    float _qi = wh_i0 * ha0;                                              \
    _qi = __builtin_fmaf(wh_i1, ha1, _qi);                                \
    _qi = __builtin_fmaf(wh_i2, ha2, _qi);                                \
    float _pf = __builtin_fmaf(wi_f0, _x0, b_f);                          \
    _pf = __builtin_fmaf(wi_f1, _x1, _pf);                                \
    _pf = __builtin_fmaf(wi_f2, _x2, _pf);                                \
    float _qf = wh_f0 * ha0;                                              \
    _qf = __builtin_fmaf(wh_f1, ha1, _qf);                                \
    _qf = __builtin_fmaf(wh_f2, ha2, _qf);                                \
    float _pg = __builtin_fmaf(wi_g0, _x0, b_g);                          \
    _pg = __builtin_fmaf(wi_g1, _x1, _pg);                                \
    _pg = __builtin_fmaf(wi_g2, _x2, _pg);                                \
    float _qg = wh_g0 * ha0;                                              \
    _qg = __builtin_fmaf(wh_g1, ha1, _qg);                                \
    _qg = __builtin_fmaf(wh_g2, ha2, _qg);                                \
    float _po = __builtin_fmaf(wi_o0, _x0, b_o);                          \
    _po = __builtin_fmaf(wi_o1, _x1, _po);                                \
    _po = __builtin_fmaf(wi_o2, _x2, _po);                                \
    float _qo = wh_o0 * ha0;                                              \
    _qo = __builtin_fmaf(wh_o1, ha1, _qo);                                \
    _qo = __builtin_fmaf(wh_o2, ha2, _qo);                                \
    float _ig = act_(_pi + _qi);                                          \
    float _fg = act_(_pf + _qf);                                          \
    float _gg = __builtin_fmaf(2.f, act_(_pg + _qg), -1.f);               \
    float _og = act_(_po + _qo);                                          \
    c = __builtin_fmaf(_fg, c, _ig * _gg);                                \
    float _th = __builtin_fmaf(                                           \
        2.f, rcp_(1.f + exp2_(-2.f * LOG2E * c)), -1.f);                  \
    h = _og * _th;                                                        \
    ha0 = QP0(h); ha1 = QP1(h); ha2 = QP2(h);                             \
    HOUT = h; } while (0)

  // step s of a block uses dwords 3s..3s+2 of the 24-dword block
#define S0(R0,R1,R2,R3,R4,R5) STEPS(R0.x, R0.y, R0.z, hs0)
#define S1(R0,R1,R2,R3,R4,R5) STEPS(R0.w, R1.x, R1.y, hs1)
#define S2(R0,R1,R2,R3,R4,R5) STEPS(R1.z, R1.w, R2.x, hs2)
#define S3(R0,R1,R2,R3,R4,R5) STEPS(R2.y, R2.z, R2.w, hs3)
#define S4(R0,R1,R2,R3,R4,R5) STEPS(R3.x, R3.y, R3.z, hs4)
#define S5(R0,R1,R2,R3,R4,R5) STEPS(R3.w, R4.x, R4.y, hs5)
#define S6(R0,R1,R2,R3,R4,R5) STEPS(R4.z, R4.w, R5.x, hs6)
#define S7(R0,R1,R2,R3,R4,R5) STEPS(R5.y, R5.z, R5.w, hs7)

#define PROCQ(R0,R1,R2,R3,R4,R5) do {                                     \
    if (DIRB) {                                                           \
      S7(R0,R1,R2,R3,R4,R5); S6(R0,R1,R2,R3,R4,R5);                       \
      S5(R0,R1,R2,R3,R4,R5); S4(R0,R1,R2,R3,R4,R5);                       \
      S3(R0,R1,R2,R3,R4,R5); S2(R0,R1,R2,R3,R4,R5);                       \
      S1(R0,R1,R2,R3,R4,R5); S0(R0,R1,R2,R3,R4,R5);                       \
    } else {                                                              \
      S0(R0,R1,R2,R3,R4,R5); S1(R0,R1,R2,R3,R4,R5);                       \
      S2(R0,R1,R2,R3,R4,R5); S3(R0,R1,R2,R3,R4,R5);                       \
      S4(R0,R1,R2,R3,R4,R5); S5(R0,R1,R2,R3,R4,R5);                       \
      S6(R0,R1,R2,R3,R4,R5); S7(R0,R1,R2,R3,R4,R5);                       \
    } } while (0)

#define STQ(blk) do {                                                     \
    if (jl < 3) {                                                         \
      float4* _o = (float4*)(ybase + (blk) * 24);                         \
      _o[0] = make_float4(hs0, hs1, hs2, hs3);                            \
      _o[1] = make_float4(hs4, hs5, hs6, hs7);                            \
    } } while (0)

#define BLK(k) (DIRB ? (63 - (k)) : (k))

  LDQ(BLK(0), p0, p1, p2, p3, p4, p5);
  LDQ(BLK(1), q0, q1, q2, q3, q4, q5);
  for (int k = 0; k < 64; k += 2) {
    PROCQ(p0, p1, p2, p3, p4, p5);
    STQ(BLK(k));
    if (k + 2 < 64) LDQ(BLK(k + 2), p0, p1, p2, p3, p4, p5);
    PROCQ(q0, q1, q2, q3, q4, q5);
    STQ(BLK(k + 1));
    if (k + 3 < 64) LDQ(BLK(k + 3), q0, q1, q2, q3, q4, q5);
  }
#undef LDQ
#undef STEPS
#undef S0
#undef S1
#undef S2
#undef S3
#undef S4
#undef S5
#undef S6
#undef S7
#undef PROCQ
#undef STQ
#undef BLK
}

__global__ __launch_bounds__(256) void lstm_l0_scalar(
    const float* __restrict__ x,
    const float* __restrict__ Wf_ih, const float* __restrict__ Wf_hh,
    const float* __restrict__ bf_ih, const float* __restrict__ bf_hh,
    const float* __restrict__ Wr_ih, const float* __restrict__ Wr_hh,
    const float* __restrict__ br_ih, const float* __restrict__ br_hh,
    float* __restrict__ y0f, float* __restrict__ y0b)
{
  int gid = blockIdx.x * 256 + threadIdx.x;
  const int nfwd = B_ * 4;             // multiple of 256 -> wave-uniform split
  if (gid < nfwd) {
    int b = gid >> 2, jl = gid & 3;
    l0_run<false>(x, Wf_ih, Wf_hh, bf_ih, bf_hh, y0f, b, jl);
  } else {
    int g2 = gid - nfwd;
    int b = g2 >> 2, jl = g2 & 3;
    l0_run<true>(x, Wr_ih, Wr_hh, br_ih, br_hh, y0b, b, jl);
  }
}

// ======= Kernel B: layer-1 fwd + epilogue (round-9 structure + pins) ========
#define CELL_TAIL(HOUT)                                                   \
    float r0v = act_(pv.x);                                               \
    float ayv = act_(pv.y);                                               \
    float axv = __builtin_fmaf(avx, r0v, dvx);                            \
    float slx = dppf<SHL4>(axv), sly = dppf<SHL4>(ayv);                   \
    float srx = dppf<SHR4>(axv), sry = dppf<SHR4>(ayv);                   \
    float pig = axv * (qgo ? srx : slx);                                  \
    float gf  = qgo ? sry : ayv;                                          \
    float gO  = qgo ? ayv : sly;                                          \
    c = __builtin_fmaf(gf, c, pig);                                       \
    float th = __builtin_fmaf(                                            \
        2.f, rcp_(1.f + exp2_(-2.f * LOG2E * c)), -1.f);                  \
    h = gO * th;                                                          \
    ha0 = QP0(h); ha1 = QP1(h); ha2 = QP2(h);                             \
    HOUT = h;

__global__ __launch_bounds__(256) void lstm_l1_fwd(
    const float* __restrict__ Wih1, const float* __restrict__ Whh1,
    const float* __restrict__ bih1, const float* __restrict__ bhh1,
    const float* __restrict__ Wih1r,
    const float* __restrict__ bih1r, const float* __restrict__ bhh1r,
    const float* __restrict__ Wlin, const float* __restrict__ blin,
    const float* __restrict__ y0f, const float* __restrict__ y0b,
    float* __restrict__ out)
{
  int tid  = blockIdx.x * 256 + threadIdx.x;
  int b    = tid >> 3;
  int lane = tid & 7;
  bool qgo = (lane & 4) != 0;
  int j = lane & 3; int jj = (j < 3) ? j : 0;
  const int ra = (qgo ? 6 : 0) + jj, rb = ra + 3;
  const float kx = qgo ? (-2.f * LOG2E) : (-LOG2E);
  const float ky = -LOG2E;
  const float avx = qgo ? 2.f : 1.f;
  const float dvx = qgo ? -1.f : 0.f;

  v2f w0 = {Wih1[ra*6+0]*kx, Wih1[rb*6+0]*ky},
      w1 = {Wih1[ra*6+1]*kx, Wih1[rb*6+1]*ky},
      w2 = {Wih1[ra*6+2]*kx, Wih1[rb*6+2]*ky},
      w3 = {Wih1[ra*6+3]*kx, Wih1[rb*6+3]*ky},
      w4 = {Wih1[ra*6+4]*kx, Wih1[rb*6+4]*ky},
      w5 = {Wih1[ra*6+5]*kx, Wih1[rb*6+5]*ky};
  v2f u0 = {Whh1[ra*3+0]*kx, Whh1[rb*3+0]*ky},
      u1 = {Whh1[ra*3+1]*kx, Whh1[rb*3+1]*ky},
      u2 = {Whh1[ra*3+2]*kx, Whh1[rb*3+2]*ky};
  v2f b2 = {(bih1[ra]+bhh1[ra])*kx, (bih1[rb]+bhh1[rb])*ky};
  PIN2(w0); PIN2(w1); PIN2(w2); PIN2(w3); PIN2(w4); PIN2(w5);
  PIN2(u0); PIN2(u1); PIN2(u2); PIN2(b2);

  const float4* yfq = (const float4*)(y0f + (size_t)b * (T_ * 3));
  const float4* ybq = (const float4*)(y0b + (size_t)b * (T_ * 3));

  const float* ufp = y0f + (size_t)b * (T_ * 3) + 63 * 24 + 7;
  const float* ubp = y0b + (size_t)b * (T_ * 3) + 63 * 24 + 7;

  float h = 0.f, c = 0.f, ha0 = 0.f, ha1 = 0.f, ha2 = 0.f;
  float hs0, hs1, hs2, hs3, hs4, hs5, hs6, hs7;
  float4 pf0, pf1, pf2, pf3, pf4, pf5, pb0, pb1, pb2, pb3, pb4, pb5;
  float4 qf0, qf1, qf2, qf3, qf4, qf5, qb0, qb1, qb2, qb3, qb4, qb5;

#define LDB(blk, F0,F1,F2,F3,F4,F5, G0,G1,G2,G3,G4,G5) do {               \
    const float4* _f = yfq + (blk) * 6;                                   \
    const float4* _g = ybq + (blk) * 6;                                   \
    F0 = _f[0]; F1 = _f[1]; F2 = _f[2];                                   \
    F3 = _f[3]; F4 = _f[4]; F5 = _f[5];                                   \
    G0 = _g[0]; G1 = _g[1]; G2 = _g[2];                                   \
    G3 = _g[3]; G4 = _g[4]; G5 = _g[5];                                   \
    __builtin_amdgcn_sched_barrier(0); } while (0)

#define STEPB(f0, f1, f2, g0, g1, g2, HOUT) do {                          \
    v2f pv = pkfma(w0, (f0), b2); pv = pkfma(w1, (f1), pv);               \
    pv = pkfma(w2, (f2), pv);                                             \
    v2f nv = w3 * sp(g0); nv = pkfma(w4, (g1), nv);                       \
    nv = pkfma(w5, (g2), nv);                                             \
    v2f uv = u0 * sp(ha0); uv = pkfma(u1, ha1, uv);                       \
    uv = pkfma(u2, ha2, uv);                                              \
    pv = (pv + nv) + uv;                                                  \
    CELL_TAIL(HOUT) } while (0)

#define PROCB(F0,F1,F2,F3,F4,F5, G0,G1,G2,G3,G4,G5) do {                  \
    STEPB(F0.x, F2.x, F4.x,  G0.x, G2.x, G4.x, hs0);                      \
    STEPB(F0.y, F2.y, F4.y,  G0.y, G2.y, G4.y, hs1);                      \
    STEPB(F0.z, F2.z, F4.z,  G0.z, G2.z, G4.z, hs2);                      \
    STEPB(F0.w, F2.w, F4.w,  G0.w, G2.w, G4.w, hs3);                      \
    STEPB(F1.x, F3.x, F5.x,  G1.x, G3.x, G5.x, hs4);                      \
    STEPB(F1.y, F3.y, F5.y,  G1.y, G3.y, G5.y, hs5);                      \
    STEPB(F1.z, F3.z, F5.z,  G1.z, G3.z, G5.z, hs6);                      \
    STEPB(F1.w, F3.w, F5.w,  G1.w, G3.w, G5.w, hs7); } while (0)

  LDB(0, pf0,pf1,pf2,pf3,pf4,pf5, pb0,pb1,pb2,pb3,pb4,pb5);
  LDB(1, qf0,qf1,qf2,qf3,qf4,qf5, qb0,qb1,qb2,qb3,qb4,qb5);
  for (int it = 0; it < 32; ++it) {
    PROCB(pf0,pf1,pf2,pf3,pf4,pf5, pb0,pb1,pb2,pb3,pb4,pb5);
    if (it < 31) LDB(2*it+2, pf0,pf1,pf2,pf3,pf4,pf5, pb0,pb1,pb2,pb3,pb4,pb5);
    PROCB(qf0,qf1,qf2,qf3,qf4,qf5, qb0,qb1,qb2,qb3,qb4,qb5);
    if (it < 31) LDB(2*it+3, qf0,qf1,qf2,qf3,qf4,qf5, qb0,qb1,qb2,qb3,qb4,qb5);
  }
  (void)hs0; (void)hs1; (void)hs2; (void)hs3;
  (void)hs4; (void)hs5; (void)hs6; (void)hs7;

  float uf0 = ufp[0], uf1 = ufp[8], uf2 = ufp[16];
  float ub0 = ubp[0], ub1 = ubp[8], ub2 = ubp[16];

  float h1b;
  {
    v2f r0 = {Wih1r[ra*6+0]*kx, Wih1r[rb*6+0]*ky},
        r1 = {Wih1r[ra*6+1]*kx, Wih1r[rb*6+1]*ky},
        r2 = {Wih1r[ra*6+2]*kx, Wih1r[rb*6+2]*ky},
        r3 = {Wih1r[ra*6+3]*kx, Wih1r[rb*6+3]*ky},
        r4 = {Wih1r[ra*6+4]*kx, Wih1r[rb*6+4]*ky},
        r5 = {Wih1r[ra*6+5]*kx, Wih1r[rb*6+5]*ky};
    v2f br = {(bih1r[ra]+bhh1r[ra])*kx, (bih1r[rb]+bhh1r[rb])*ky};
    v2f qv = pkfma(r0, uf0, br); qv = pkfma(r1, uf1, qv);
    qv = pkfma(r2, uf2, qv);     qv = pkfma(r3, ub0, qv);
    qv = pkfma(r4, ub1, qv);     qv = pkfma(r5, ub2, qv);
    float r0v = act_(qv.x);
    float ayv = act_(qv.y);
    float axv = __builtin_fmaf(avx, r0v, dvx);
    float slx = dppf<SHL4>(axv), sly = dppf<SHL4>(ayv);
    float srx = dppf<SHR4>(axv);
    float gi = qgo ? srx : axv;
    float gG = qgo ? axv : slx;
    float gO = qgo ? ayv : sly;
    float cb = gi * gG;
    h1b = gO * tanh_(cb);
  }

  float part = 0.f;
  if (!qgo && j < 3) part = __builtin_fmaf(Wlin[j], h, Wlin[3 + j] * h1b);
  part += __shfl_xor(part, 1, 8);
  part += __shfl_xor(part, 2, 8);
  part += __shfl_xor(part, 4, 8);
  if (lane == 0) out[b] = sigm_(part + blin[0]);
#undef LDB
#undef STEPB
#undef PROCB
}

extern "C" void kernel_launch(void* const* d_in, const int* in_sizes, int n_in,
                              void* d_out, int out_size, void* d_ws, size_t ws_size,
                              hipStream_t stream) {
  const float* x        = (const float*)d_in[0];
  const float* W_ih_l0  = (const float*)d_in[1];
  const float* W_hh_l0  = (const float*)d_in[2];
  const float* b_ih_l0  = (const float*)d_in[3];
  const float* b_hh_l0  = (const float*)d_in[4];
  const float* W_ih_l0r = (const float*)d_in[5];
  const float* W_hh_l0r = (const float*)d_in[6];
  const float* b_ih_l0r = (const float*)d_in[7];
  const float* b_hh_l0r = (const float*)d_in[8];
  const float* W_ih_l1  = (const float*)d_in[9];
  const float* W_hh_l1  = (const float*)d_in[10];
  const float* b_ih_l1  = (const float*)d_in[11];
  const float* b_hh_l1  = (const float*)d_in[12];
  const float* W_ih_l1r = (const float*)d_in[13];
  const float* b_ih_l1r = (const float*)d_in[15];
  const float* b_hh_l1r = (const float*)d_in[16];
  const float* W_lin    = (const float*)d_in[17];
  const float* b_lin    = (const float*)d_in[18];

  float* y0f = (float*)d_ws;                        // 48 MB
  float* y0b = (float*)d_ws + (size_t)B_ * T_ * 3;  // 48 MB
  float* out = (float*)d_out;

  // KA: fwd + bwd in one launch = 1024 waves (1 wave/SIMD)
  lstm_l0_scalar<<<(B_ * 4 * 2) / 256, 256, 0, stream>>>(
      x, W_ih_l0, W_hh_l0, b_ih_l0, b_hh_l0,
      W_ih_l0r, W_hh_l0r, b_ih_l0r, b_hh_l0r, y0f, y0b);

  // KB: 8 lanes/batch = 1024 waves
  lstm_l1_fwd<<<(B_ * 8) / 256, 256, 0, stream>>>(
      W_ih_l1, W_hh_l1, b_ih_l1, b_hh_l1,
      W_ih_l1r, b_ih_l1r, b_hh_l1r,
      W_lin, b_lin, y0f, y0b, out);
}